// Round 1
// baseline (103.581 us; speedup 1.0000x reference)
//
#include <hip/hip_runtime.h>
#include <hip/hip_bf16.h>

typedef __attribute__((ext_vector_type(8))) short bf16x8;
typedef __attribute__((ext_vector_type(16))) float f32x16;

#define NHID 256
#define NDIM 128
#define NB   512

__device__ __forceinline__ unsigned pk2bf(float a, float b) {
  float2 f; f.x = a; f.y = b;
  __hip_bfloat162 h = __float22bfloat162_rn(f);
  unsigned r;
  __builtin_memcpy(&r, &h, 4);
  return r;
}

// ---------------- setup ----------------
// hx = x@Wx^T + b0, hy = y@Wy^T  (4 rows per block: W0 row is loaded once, reused 4x)
// W1/W2 -> bf16 fragment-major for 32x32x16 MFMA:
//   frag f = kt*8 + gtile  (kt = k>>4, gtile = g>>5), 1 KB each.
//   lane l = (g&31) + 32*((k>>3)&1) holds W[g][kt*16 + (l>>5)*8 .. +8] as 8 bf16 at l*16 bytes.
__global__ void k_setup(const float* __restrict__ x, const float* __restrict__ y,
                        const float* __restrict__ W0, const float* __restrict__ b0,
                        const float* __restrict__ W1, const float* __restrict__ W2,
                        float* __restrict__ hx, float* __restrict__ hy,
                        unsigned short* __restrict__ W1f, unsigned short* __restrict__ W2f) {
  int bid = blockIdx.x, tid = threadIdx.x;
  if (bid < 256) {
    int which = bid & 1;                 // 0: hx (+b0), 1: hy
    int rowbase = (bid >> 1) * 4;
    const float* in = which ? y : x;
    const float4* wr = (const float4*)(W0 + tid * (2 * NDIM) + which * NDIM);
    const float4* x0 = (const float4*)(in + (rowbase + 0) * NDIM);
    const float4* x1 = (const float4*)(in + (rowbase + 1) * NDIM);
    const float4* x2 = (const float4*)(in + (rowbase + 2) * NDIM);
    const float4* x3 = (const float4*)(in + (rowbase + 3) * NDIM);
    float s0 = 0.f, s1 = 0.f, s2 = 0.f, s3 = 0.f;
#pragma unroll 4
    for (int i = 0; i < NDIM / 4; ++i) {
      float4 b = wr[i];
      float4 a;
      a = x0[i]; s0 += a.x * b.x + a.y * b.y + a.z * b.z + a.w * b.w;
      a = x1[i]; s1 += a.x * b.x + a.y * b.y + a.z * b.z + a.w * b.w;
      a = x2[i]; s2 += a.x * b.x + a.y * b.y + a.z * b.z + a.w * b.w;
      a = x3[i]; s3 += a.x * b.x + a.y * b.y + a.z * b.z + a.w * b.w;
    }
    float bb = which ? 0.f : b0[tid];
    float* o = (which ? hy : hx) + rowbase * NHID + tid;
    o[0]        = s0 + bb;
    o[NHID]     = s1 + bb;
    o[2 * NHID] = s2 + bb;
    o[3 * NHID] = s3 + bb;
  } else {
    int i = ((bid - 256) * 256 + tid) * 4;        // 2*65536 elements total
    const float* src = W1; unsigned short* dst = W1f; int j = i;
    if (i >= NHID * NHID) { src = W2; dst = W2f; j = i - NHID * NHID; }
    float4 v = *(const float4*)(src + j);
    int g = j >> 8, k0 = j & 255;                 // 4 consecutive k, same g
    int f = ((k0 >> 4) << 3) + (g >> 5);
    int l = (g & 31) + (((k0 >> 3) & 1) << 5);
    uint2 pk; pk.x = pk2bf(v.x, v.y); pk.y = pk2bf(v.z, v.w);
    *(uint2*)(dst + f * 512 + l * 8 + (k0 & 7)) = pk;
  }
}

// ---------------- layer compute: wave tile 64g x 64m, 32x32x16 MFMA ----------------
// LDS h fragment-major: frag(kt, mtile) at (kt*4 + mtile)*1024 bytes (kt in [0,16), mtile in [0,4)),
//   lane's 16B at lane*16 holds h[m = mtile*32 + (lane&31)][k = kt*16 + (lane>>5)*8 .. +8].
// Wave (wg, wm): g in [wg*64, +64), m in [wm*64, +64).
__device__ __forceinline__ void layer_compute(const unsigned short* __restrict__ Wf,
                                              const char* __restrict__ src_lane, // buf + wm*2048 + lane*16
                                              f32x16 acc[2][2], int wg, int lane) {
#pragma unroll
  for (int i = 0; i < 2; ++i)
#pragma unroll
    for (int j = 0; j < 2; ++j)
#pragma unroll
      for (int e = 0; e < 16; ++e) acc[i][j][e] = 0.f;

  const unsigned short* fb = Wf + wg * 1024 + lane * 8;   // + kt*4096 + gt*512 (ushort units)

#pragma unroll 4
  for (int kt = 0; kt < 16; ++kt) {
    bf16x8 A0 = *(const bf16x8*)(fb + kt * 4096);
    bf16x8 A1 = *(const bf16x8*)(fb + kt * 4096 + 512);
    bf16x8 B0 = *(const bf16x8*)(src_lane + kt * 4096);
    bf16x8 B1 = *(const bf16x8*)(src_lane + kt * 4096 + 1024);
    acc[0][0] = __builtin_amdgcn_mfma_f32_32x32x16_bf16(A0, B0, acc[0][0], 0, 0, 0);
    acc[0][1] = __builtin_amdgcn_mfma_f32_32x32x16_bf16(A0, B1, acc[0][1], 0, 0, 0);
    acc[1][0] = __builtin_amdgcn_mfma_f32_32x32x16_bf16(A1, B0, acc[1][0], 0, 0, 0);
    acc[1][1] = __builtin_amdgcn_mfma_f32_32x32x16_bf16(A1, B1, acc[1][1], 0, 0, 0);
  }
}

// ---------------- main fused kernel: 128 pairs (8 a x 16 b) per block, 512 threads ----------------
__global__ __launch_bounds__(512, 4) void k_main(
    const float* __restrict__ hx, const float* __restrict__ hy,
    const unsigned short* __restrict__ W1f, const unsigned short* __restrict__ W2f,
    const float* __restrict__ bias1, const float* __restrict__ bias2,
    const float* __restrict__ w3, const float* __restrict__ b3,
    float* __restrict__ out) {
  __shared__ __align__(16) char buf[65536];   // h0 -> h1 (in place), then out-staging

  const int tid = threadIdx.x;
  const int bid = blockIdx.x;
  const int a0  = (bid >> 5) * 8;    // 64 a-tile groups of 8
  const int bb0 = (bid & 31) * 16;   // 32 b-tile groups

  const int lane = tid & 63, wv = tid >> 6;
  const int c = lane & 31, l5 = lane >> 5;
  const int wg = wv >> 1, wm = wv & 1;    // wave tile: g in [wg*64,+64), m in [wm*64,+64)

  // ---- build h0: thread (wv, lane) fills 16B of frag(kt, mtile=wv&3) for 8 kt values ----
  // h0[m][k] = relu(hx'[a0 + m>>4][k] + hy[bb0 + (m&15)][k])
  {
    int mt_b = wv & 3;
    int kbase = (wv >> 2) * 8;           // kt range [kbase, kbase+8)
    int m = mt_b * 32 + c;
    const float* pxr = hx + (a0 + (m >> 4)) * NHID + l5 * 8;
    const float* pyr = hy + (bb0 + (m & 15)) * NHID + l5 * 8;
    char* wbase = buf + (kbase * 4 + mt_b) * 1024 + lane * 16;
#pragma unroll
    for (int j = 0; j < 8; ++j) {
      int ko = (kbase + j) * 16;
      float4 x0 = *(const float4*)(pxr + ko);
      float4 x1 = *(const float4*)(pxr + ko + 4);
      float4 y0 = *(const float4*)(pyr + ko);
      float4 y1 = *(const float4*)(pyr + ko + 4);
      uint4 pk;
      pk.x = pk2bf(fmaxf(x0.x + y0.x, 0.f), fmaxf(x0.y + y0.y, 0.f));
      pk.y = pk2bf(fmaxf(x0.z + y0.z, 0.f), fmaxf(x0.w + y0.w, 0.f));
      pk.z = pk2bf(fmaxf(x1.x + y1.x, 0.f), fmaxf(x1.y + y1.y, 0.f));
      pk.w = pk2bf(fmaxf(x1.z + y1.z, 0.f), fmaxf(x1.w + y1.w, 0.f));
      *(uint4*)(wbase + j * 4096) = pk;
    }
  }
  __syncthreads();

  const char* src_lane = buf + wm * 2048 + lane * 16;
  f32x16 acc[2][2];

  // ---- layer 1 ----
  layer_compute(W1f, src_lane, acc, wg, lane);
  __syncthreads();

  // ---- layer-1 epilogue: h1[m][g] = relu(acc + b1) back into fragment-major LDS ----
  // Element (g = wg*64 + gt*32 + (r&3) + 8*(r>>2) + 4*l5, m = wm*64 + mt*32 + c):
  //   frag f' = (g>>4)*4 + (m>>5), lane slot l' = c + 32*(rg&1), byte l'*16 + (g&7)*2.
  // Per (gt, rg, mt): one contiguous 8B store of 4 bf16 (regs rg*4..rg*4+3).
  {
    const int gb = wg * 64;
#pragma unroll
    for (int gt = 0; gt < 2; ++gt) {
#pragma unroll
      for (int rg = 0; rg < 4; ++rg) {
        float4 bv = *(const float4*)(bias1 + gb + gt * 32 + rg * 8 + l5 * 4);
        int fbase = (wg * 4 + gt * 2 + (rg >> 1)) * 4 + wm * 2;
        char* wa = buf + (c + ((rg & 1) << 5)) * 16 + l5 * 8;
#pragma unroll
        for (int mt = 0; mt < 2; ++mt) {
          f32x16 v = acc[gt][mt];
          uint2 pk;
          pk.x = pk2bf(fmaxf(v[rg * 4 + 0] + bv.x, 0.f), fmaxf(v[rg * 4 + 1] + bv.y, 0.f));
          pk.y = pk2bf(fmaxf(v[rg * 4 + 2] + bv.z, 0.f), fmaxf(v[rg * 4 + 3] + bv.w, 0.f));
          *(uint2*)(wa + (fbase + mt) * 1024) = pk;
        }
      }
    }
  }
  __syncthreads();

  // ---- layer 2 + head folded into registers ----
  layer_compute(W2f, src_lane, acc, wg, lane);

  float s0 = 0.f, s1 = 0.f;   // partial out for m = wm*64 + {0,1}*32 + c
  {
    const int gb = wg * 64;
#pragma unroll
    for (int gt = 0; gt < 2; ++gt) {
#pragma unroll
      for (int rg = 0; rg < 4; ++rg) {
        int g0 = gb + gt * 32 + rg * 8 + l5 * 4;
        float4 bv  = *(const float4*)(bias2 + g0);
        float4 wvv = *(const float4*)(w3 + g0);
        f32x16 v0 = acc[gt][0], v1 = acc[gt][1];
        s0 += fmaxf(v0[rg * 4 + 0] + bv.x, 0.f) * wvv.x + fmaxf(v0[rg * 4 + 1] + bv.y, 0.f) * wvv.y
            + fmaxf(v0[rg * 4 + 2] + bv.z, 0.f) * wvv.z + fmaxf(v0[rg * 4 + 3] + bv.w, 0.f) * wvv.w;
        s1 += fmaxf(v1[rg * 4 + 0] + bv.x, 0.f) * wvv.x + fmaxf(v1[rg * 4 + 1] + bv.y, 0.f) * wvv.y
            + fmaxf(v1[rg * 4 + 2] + bv.z, 0.f) * wvv.z + fmaxf(v1[rg * 4 + 3] + bv.w, 0.f) * wvv.w;
      }
    }
  }
  // reduce over the two l5 halves (different g-quads, same m)
  s0 += __shfl_xor(s0, 32);
  s1 += __shfl_xor(s1, 32);

  __syncthreads();                    // all LDS reads of layer-2 done; reuse buf as staging
  float* stg = (float*)buf;           // [4 wg][128 m]
  if (l5 == 0) {
    stg[wg * 128 + wm * 64 + c]      = s0;
    stg[wg * 128 + wm * 64 + 32 + c] = s1;
  }
  __syncthreads();

  if (tid < 128) {
    float v = b3[0];
#pragma unroll
    for (int i = 0; i < 4; ++i) v += stg[i * 128 + tid];
    out[(a0 + (tid >> 4)) * NB + bb0 + (tid & 15)] = v;
  }
}

extern "C" void kernel_launch(void* const* d_in, const int* in_sizes, int n_in,
                              void* d_out, int out_size, void* d_ws, size_t ws_size,
                              hipStream_t stream) {
  const float* x  = (const float*)d_in[0];
  const float* y  = (const float*)d_in[1];
  const float* W0 = (const float*)d_in[2];
  const float* b0 = (const float*)d_in[3];
  const float* W1 = (const float*)d_in[4];
  const float* b1 = (const float*)d_in[5];
  const float* W2 = (const float*)d_in[6];
  const float* b2 = (const float*)d_in[7];
  const float* W3 = (const float*)d_in[8];
  const float* b3 = (const float*)d_in[9];
  float* out = (float*)d_out;

  char* ws = (char*)d_ws;
  float* hx = (float*)ws;                               // 512*256*4 = 512 KB
  float* hy = (float*)(ws + 524288);                    // 512 KB
  unsigned short* W1f = (unsigned short*)(ws + 1048576);          // 128 KB
  unsigned short* W2f = (unsigned short*)(ws + 1048576 + 131072); // 128 KB

  k_setup<<<dim3(384), dim3(256), 0, stream>>>(x, y, W0, b0, W1, W2, hx, hy, W1f, W2f);
  k_main<<<dim3(2048), dim3(512), 0, stream>>>(hx, hy, W1f, W2f, b1, b2, W3, b3, out);
}

// Round 2
// 94.855 us; speedup vs baseline: 1.0920x; 1.0920x over previous
//
#include <hip/hip_runtime.h>
#include <hip/hip_bf16.h>

typedef __attribute__((ext_vector_type(8))) short bf16x8;
typedef __attribute__((ext_vector_type(4))) float f32x4;
typedef __attribute__((ext_vector_type(16))) float f32x16;

#define NHID 256
#define NDIM 128
#define NB   512

__device__ __forceinline__ unsigned pk2bf(float a, float b) {
  float2 f; f.x = a; f.y = b;
  __hip_bfloat162 h = __float22bfloat162_rn(f);
  unsigned r;
  __builtin_memcpy(&r, &h, 4);
  return r;
}

// ---------------- setup ----------------
// hx = x@Wx^T + b0, hy = y@Wy^T  (8 rows per block: W0 row loaded once, reused 8x)
// W1/W2 -> bf16 fragment-major for 32x32x16 MFMA:
//   frag f = kt*8 + gtile  (kt = k>>4, gtile = g>>5), 1 KB each.
//   lane l = (g&31) + 32*((k>>3)&1) holds W[g][kt*16 + (l>>5)*8 .. +8] as 8 bf16 at l*16 bytes.
__global__ void k_setup(const float* __restrict__ x, const float* __restrict__ y,
                        const float* __restrict__ W0, const float* __restrict__ b0,
                        const float* __restrict__ W1, const float* __restrict__ W2,
                        float* __restrict__ hx, float* __restrict__ hy,
                        unsigned short* __restrict__ W1f, unsigned short* __restrict__ W2f) {
  int bid = blockIdx.x, tid = threadIdx.x;
  if (bid < 128) {
    int which = bid & 1;                 // 0: hx (+b0), 1: hy
    int rowbase = (bid >> 1) * 8;
    const float* in = which ? y : x;
    const f32x4* wr = (const f32x4*)(W0 + tid * (2 * NDIM) + which * NDIM);
    f32x4 sv[8];
#pragma unroll
    for (int r = 0; r < 8; ++r) sv[r] = f32x4{0.f, 0.f, 0.f, 0.f};
#pragma unroll 4
    for (int i = 0; i < NDIM / 4; ++i) {
      f32x4 b = wr[i];
#pragma unroll
      for (int r = 0; r < 8; ++r) {
        f32x4 a = *(const f32x4*)(in + (rowbase + r) * NDIM + i * 4);
        sv[r] += a * b;
      }
    }
    float bb = which ? 0.f : b0[tid];
    float* o = (which ? hy : hx) + rowbase * NHID + tid;
#pragma unroll
    for (int r = 0; r < 8; ++r)
      o[r * NHID] = sv[r][0] + sv[r][1] + sv[r][2] + sv[r][3] + bb;
  } else {
    int i = ((bid - 128) * 256 + tid) * 4;        // 2*65536 elements total
    const float* src = W1; unsigned short* dst = W1f; int j = i;
    if (i >= NHID * NHID) { src = W2; dst = W2f; j = i - NHID * NHID; }
    float4 v = *(const float4*)(src + j);
    int g = j >> 8, k0 = j & 255;                 // 4 consecutive k, same g
    int f = ((k0 >> 4) << 3) + (g >> 5);
    int l = (g & 31) + (((k0 >> 3) & 1) << 5);
    uint2 pk; pk.x = pk2bf(v.x, v.y); pk.y = pk2bf(v.z, v.w);
    *(uint2*)(dst + f * 512 + l * 8 + (k0 & 7)) = pk;
  }
}

// ---------------- layer compute: wave tile 32g x 128m, 32x32x16 MFMA ----------------
// LDS h fragment-major: frag(kt, mt) at (kt*4 + mt)*1024 bytes (kt in [0,16), mt in [0,4)),
//   lane's 16B at lane*16 holds h[m = mt*32 + (lane&31)][k = kt*16 + (lane>>5)*8 .. +8].
// Wave wv: g in [wv*32, +32), m in [0,128).  1 A load + 4 B loads + 4 MFMA per kt.
__device__ __forceinline__ void layer_compute(const unsigned short* __restrict__ Wf,
                                              const char* __restrict__ src_lane, // buf + lane*16
                                              f32x16 acc[4], int wv, int lane) {
#pragma unroll
  for (int j = 0; j < 4; ++j)
#pragma unroll
    for (int e = 0; e < 16; ++e) acc[j][e] = 0.f;

  const unsigned short* fb = Wf + wv * 512 + lane * 8;   // + kt*4096 (ushort units)

#pragma unroll 4
  for (int kt = 0; kt < 16; ++kt) {
    bf16x8 A  = *(const bf16x8*)(fb + kt * 4096);
    bf16x8 B0 = *(const bf16x8*)(src_lane + kt * 4096);
    bf16x8 B1 = *(const bf16x8*)(src_lane + kt * 4096 + 1024);
    bf16x8 B2 = *(const bf16x8*)(src_lane + kt * 4096 + 2048);
    bf16x8 B3 = *(const bf16x8*)(src_lane + kt * 4096 + 3072);
    acc[0] = __builtin_amdgcn_mfma_f32_32x32x16_bf16(A, B0, acc[0], 0, 0, 0);
    acc[1] = __builtin_amdgcn_mfma_f32_32x32x16_bf16(A, B1, acc[1], 0, 0, 0);
    acc[2] = __builtin_amdgcn_mfma_f32_32x32x16_bf16(A, B2, acc[2], 0, 0, 0);
    acc[3] = __builtin_amdgcn_mfma_f32_32x32x16_bf16(A, B3, acc[3], 0, 0, 0);
  }
}

// ---------------- main fused kernel: 128 pairs (8 a x 16 b) per block, 512 threads ----------------
__global__ __launch_bounds__(512, 4) void k_main(
    const float* __restrict__ hx, const float* __restrict__ hy,
    const unsigned short* __restrict__ W1f, const unsigned short* __restrict__ W2f,
    const float* __restrict__ bias1, const float* __restrict__ bias2,
    const float* __restrict__ w3, const float* __restrict__ b3,
    float* __restrict__ out) {
  __shared__ __align__(16) char buf[65536];   // h0 -> h1 (in place), then out-staging

  const int tid = threadIdx.x;
  const int bid = blockIdx.x;
  const int a0  = (bid >> 5) * 8;    // 64 a-tile groups of 8
  const int bb0 = (bid & 31) * 16;   // 32 b-tile groups

  const int lane = tid & 63, wv = tid >> 6;
  const int c = lane & 31, l5 = lane >> 5;
  const f32x4 vzero = {0.f, 0.f, 0.f, 0.f};

  // ---- build h0: thread (wv, lane) fills 16B of frag(kt, mt = wv&3) for 8 kt values ----
  // h0[m][k] = relu(hx'[a0 + m>>4][k] + hy[bb0 + (m&15)][k]),  m = (wv&3)*32 + c
  {
    int mt_b = wv & 3;
    int kbase = (wv >> 2) * 8;           // kt range [kbase, kbase+8)
    int m = mt_b * 32 + c;
    const float* pxr = hx + (a0 + (m >> 4)) * NHID + l5 * 8;
    const float* pyr = hy + (bb0 + (m & 15)) * NHID + l5 * 8;
    char* wbase = buf + (kbase * 4 + mt_b) * 1024 + lane * 16;
#pragma unroll
    for (int j = 0; j < 8; ++j) {
      int ko = (kbase + j) * 16;
      f32x4 x0 = *(const f32x4*)(pxr + ko);
      f32x4 x1 = *(const f32x4*)(pxr + ko + 4);
      f32x4 y0 = *(const f32x4*)(pyr + ko);
      f32x4 y1 = *(const f32x4*)(pyr + ko + 4);
      f32x4 a = __builtin_elementwise_max(x0 + y0, vzero);
      f32x4 b = __builtin_elementwise_max(x1 + y1, vzero);
      uint4 pk;
      pk.x = pk2bf(a[0], a[1]);
      pk.y = pk2bf(a[2], a[3]);
      pk.z = pk2bf(b[0], b[1]);
      pk.w = pk2bf(b[2], b[3]);
      *(uint4*)(wbase + j * 4096) = pk;
    }
  }
  __syncthreads();

  const char* src_lane = buf + lane * 16;
  f32x16 acc[4];

  // ---- layer 1 ----
  layer_compute(W1f, src_lane, acc, wv, lane);
  __syncthreads();

  // ---- layer-1 epilogue: h1[m][g] = relu(acc + b1) back into fragment-major LDS ----
  // acc[mt][r]: m = mt*32 + c, g = wv*32 + (r&3) + 8*(r>>2) + 4*l5.
  // With rg = r>>2: g = wv*32 + rg*8 + l5*4 + (r&3) — 4 consecutive g per rg-quad.
  // Dest frag f' = (g>>4)*4 + (m>>5) = (wv*2 + (rg>>1))*4 + mt,
  //   lane slot l' = c + 32*(rg&1), byte l'*16 + l5*8 (8B store of 4 bf16).
  {
#pragma unroll
    for (int rg = 0; rg < 4; ++rg) {
      f32x4 bv = *(const f32x4*)(bias1 + wv * 32 + rg * 8 + l5 * 4);
      char* wa = buf + (c + ((rg & 1) << 5)) * 16 + l5 * 8;
      int fbase = (wv * 2 + (rg >> 1)) * 4;
#pragma unroll
      for (int mt = 0; mt < 4; ++mt) {
        f32x16 v = acc[mt];
        f32x4 t = {v[rg * 4 + 0], v[rg * 4 + 1], v[rg * 4 + 2], v[rg * 4 + 3]};
        t = __builtin_elementwise_max(t + bv, vzero);
        uint2 pk;
        pk.x = pk2bf(t[0], t[1]);
        pk.y = pk2bf(t[2], t[3]);
        *(uint2*)(wa + (fbase + mt) * 1024) = pk;
      }
    }
  }
  __syncthreads();

  // ---- layer 2 + head folded into registers ----
  layer_compute(W2f, src_lane, acc, wv, lane);

  float s[4];
  {
    f32x4 sv[4];
#pragma unroll
    for (int mt = 0; mt < 4; ++mt) sv[mt] = vzero;
#pragma unroll
    for (int rg = 0; rg < 4; ++rg) {
      int g0 = wv * 32 + rg * 8 + l5 * 4;
      f32x4 bv  = *(const f32x4*)(bias2 + g0);
      f32x4 wvv = *(const f32x4*)(w3 + g0);
#pragma unroll
      for (int mt = 0; mt < 4; ++mt) {
        f32x16 v = acc[mt];
        f32x4 t = {v[rg * 4 + 0], v[rg * 4 + 1], v[rg * 4 + 2], v[rg * 4 + 3]};
        t = __builtin_elementwise_max(t + bv, vzero);
        sv[mt] += t * wvv;
      }
    }
#pragma unroll
    for (int mt = 0; mt < 4; ++mt) {
      float t = sv[mt][0] + sv[mt][1] + sv[mt][2] + sv[mt][3];
      t += __shfl_xor(t, 32);            // combine the two l5 halves (different g-quads)
      s[mt] = t;
    }
  }

  __syncthreads();                    // all LDS reads of layer-2 done; reuse buf as staging
  float* stg = (float*)buf;           // [8 waves][128 m]
  if (l5 == 0) {
#pragma unroll
    for (int mt = 0; mt < 4; ++mt) stg[wv * 128 + mt * 32 + c] = s[mt];
  }
  __syncthreads();

  if (tid < 128) {
    float v = b3[0];
#pragma unroll
    for (int w = 0; w < 8; ++w) v += stg[w * 128 + tid];
    out[(a0 + (tid >> 4)) * NB + bb0 + (tid & 15)] = v;
  }
}

extern "C" void kernel_launch(void* const* d_in, const int* in_sizes, int n_in,
                              void* d_out, int out_size, void* d_ws, size_t ws_size,
                              hipStream_t stream) {
  const float* x  = (const float*)d_in[0];
  const float* y  = (const float*)d_in[1];
  const float* W0 = (const float*)d_in[2];
  const float* b0 = (const float*)d_in[3];
  const float* W1 = (const float*)d_in[4];
  const float* b1 = (const float*)d_in[5];
  const float* W2 = (const float*)d_in[6];
  const float* b2 = (const float*)d_in[7];
  const float* W3 = (const float*)d_in[8];
  const float* b3 = (const float*)d_in[9];
  float* out = (float*)d_out;

  char* ws = (char*)d_ws;
  float* hx = (float*)ws;                               // 512*256*4 = 512 KB
  float* hy = (float*)(ws + 524288);                    // 512 KB
  unsigned short* W1f = (unsigned short*)(ws + 1048576);          // 128 KB
  unsigned short* W2f = (unsigned short*)(ws + 1048576 + 131072); // 128 KB

  k_setup<<<dim3(256), dim3(256), 0, stream>>>(x, y, W0, b0, W1, W2, hx, hy, W1f, W2f);
  k_main<<<dim3(2048), dim3(512), 0, stream>>>(hx, hy, W1f, W2f, b1, b2, W3, b3, out);
}

// Round 3
// 93.616 us; speedup vs baseline: 1.1064x; 1.0132x over previous
//
#include <hip/hip_runtime.h>
#include <hip/hip_bf16.h>

typedef __attribute__((ext_vector_type(8))) short bf16x8;
typedef __attribute__((ext_vector_type(4))) float f32x4;
typedef __attribute__((ext_vector_type(16))) float f32x16;

#define NHID 256
#define NDIM 128
#define NB   512

__device__ __forceinline__ unsigned pk2bf(float a, float b) {
  float2 f; f.x = a; f.y = b;
  __hip_bfloat162 h = __float22bfloat162_rn(f);
  unsigned r;
  __builtin_memcpy(&r, &h, 4);
  return r;
}

// ---------------- setup ----------------
// hx = x@Wx^T + b0, hy = y@Wy^T  (8 rows per block: W0 row loaded once, reused 8x)
// W1/W2 -> bf16 fragment-major for 32x32x16 MFMA:
//   frag f = kt*8 + gtile  (kt = k>>4, gtile = g>>5), 1 KB each.
//   lane l = (g&31) + 32*((k>>3)&1) holds W[g][kt*16 + (l>>5)*8 .. +8] as 8 bf16 at l*16 bytes.
__global__ void k_setup(const float* __restrict__ x, const float* __restrict__ y,
                        const float* __restrict__ W0, const float* __restrict__ b0,
                        const float* __restrict__ W1, const float* __restrict__ W2,
                        float* __restrict__ hx, float* __restrict__ hy,
                        unsigned short* __restrict__ W1f, unsigned short* __restrict__ W2f) {
  int bid = blockIdx.x, tid = threadIdx.x;
  if (bid < 128) {
    int which = bid & 1;                 // 0: hx (+b0), 1: hy
    int rowbase = (bid >> 1) * 8;
    const float* in = which ? y : x;
    const f32x4* wr = (const f32x4*)(W0 + tid * (2 * NDIM) + which * NDIM);
    f32x4 sv[8];
#pragma unroll
    for (int r = 0; r < 8; ++r) sv[r] = f32x4{0.f, 0.f, 0.f, 0.f};
#pragma unroll 4
    for (int i = 0; i < NDIM / 4; ++i) {
      f32x4 b = wr[i];
#pragma unroll
      for (int r = 0; r < 8; ++r) {
        f32x4 a = *(const f32x4*)(in + (rowbase + r) * NDIM + i * 4);
        sv[r] += a * b;
      }
    }
    float bb = which ? 0.f : b0[tid];
    float* o = (which ? hy : hx) + rowbase * NHID + tid;
#pragma unroll
    for (int r = 0; r < 8; ++r)
      o[r * NHID] = sv[r][0] + sv[r][1] + sv[r][2] + sv[r][3] + bb;
  } else {
    int i = ((bid - 128) * 256 + tid) * 4;        // 2*65536 elements total
    const float* src = W1; unsigned short* dst = W1f; int j = i;
    if (i >= NHID * NHID) { src = W2; dst = W2f; j = i - NHID * NHID; }
    float4 v = *(const float4*)(src + j);
    int g = j >> 8, k0 = j & 255;                 // 4 consecutive k, same g
    int f = ((k0 >> 4) << 3) + (g >> 5);
    int l = (g & 31) + (((k0 >> 3) & 1) << 5);
    uint2 pk; pk.x = pk2bf(v.x, v.y); pk.y = pk2bf(v.z, v.w);
    *(uint2*)(dst + f * 512 + l * 8 + (k0 & 7)) = pk;
  }
}

// ---------------- layer loop: wave tile 32g x 128m, 32x32x16 MFMA ----------------
// LDS h fragment-major: frag(kt, mt) at (kt*4 + mt)*1024 bytes, lane's 16B at lane*16 holds
//   h[m = mt*32 + (lane&31)][k = kt*16 + (lane>>5)*8 .. +8].
// A-fragments double-buffered in registers (a0/a1), prefetch distance 2:
//   A(kt+2) issued right after the MFMA quad that consumed A(kt).
// PRE2: in the final iteration, issue the first two A-fragments of the NEXT layer.
template <bool PRE2>
__device__ __forceinline__ void layer_loop(const unsigned short* __restrict__ fb,
                                           const char* __restrict__ src_lane, // buf + lane*16
                                           f32x16 acc[4],
                                           bf16x8 a0, bf16x8 a1,
                                           const unsigned short* __restrict__ fb2,
                                           bf16x8& p0, bf16x8& p1) {
#pragma unroll
  for (int j = 0; j < 4; ++j)
#pragma unroll
    for (int e = 0; e < 16; ++e) acc[j][e] = 0.f;

#pragma unroll
  for (int kt = 0; kt < 16; kt += 2) {
    {
      bf16x8 B0 = *(const bf16x8*)(src_lane + kt * 4096);
      bf16x8 B1 = *(const bf16x8*)(src_lane + kt * 4096 + 1024);
      bf16x8 B2 = *(const bf16x8*)(src_lane + kt * 4096 + 2048);
      bf16x8 B3 = *(const bf16x8*)(src_lane + kt * 4096 + 3072);
      __builtin_amdgcn_s_setprio(1);
      acc[0] = __builtin_amdgcn_mfma_f32_32x32x16_bf16(a0, B0, acc[0], 0, 0, 0);
      acc[1] = __builtin_amdgcn_mfma_f32_32x32x16_bf16(a0, B1, acc[1], 0, 0, 0);
      acc[2] = __builtin_amdgcn_mfma_f32_32x32x16_bf16(a0, B2, acc[2], 0, 0, 0);
      acc[3] = __builtin_amdgcn_mfma_f32_32x32x16_bf16(a0, B3, acc[3], 0, 0, 0);
      __builtin_amdgcn_s_setprio(0);
      if (kt + 2 < 16) a0 = *(const bf16x8*)(fb + (kt + 2) * 4096);
    }
    {
      bf16x8 B0 = *(const bf16x8*)(src_lane + (kt + 1) * 4096);
      bf16x8 B1 = *(const bf16x8*)(src_lane + (kt + 1) * 4096 + 1024);
      bf16x8 B2 = *(const bf16x8*)(src_lane + (kt + 1) * 4096 + 2048);
      bf16x8 B3 = *(const bf16x8*)(src_lane + (kt + 1) * 4096 + 3072);
      __builtin_amdgcn_s_setprio(1);
      acc[0] = __builtin_amdgcn_mfma_f32_32x32x16_bf16(a1, B0, acc[0], 0, 0, 0);
      acc[1] = __builtin_amdgcn_mfma_f32_32x32x16_bf16(a1, B1, acc[1], 0, 0, 0);
      acc[2] = __builtin_amdgcn_mfma_f32_32x32x16_bf16(a1, B2, acc[2], 0, 0, 0);
      acc[3] = __builtin_amdgcn_mfma_f32_32x32x16_bf16(a1, B3, acc[3], 0, 0, 0);
      __builtin_amdgcn_s_setprio(0);
      if (kt + 3 < 16) {
        a1 = *(const bf16x8*)(fb + (kt + 3) * 4096);
      } else if (PRE2) {
        p0 = *(const bf16x8*)(fb2);
        p1 = *(const bf16x8*)(fb2 + 4096);
      }
    }
  }
}

// ---------------- main fused kernel: 128 pairs (8 a x 16 b) per block, 512 threads ----------------
__global__ __launch_bounds__(512, 4) void k_main(
    const float* __restrict__ hx, const float* __restrict__ hy,
    const unsigned short* __restrict__ W1f, const unsigned short* __restrict__ W2f,
    const float* __restrict__ bias1, const float* __restrict__ bias2,
    const float* __restrict__ w3, const float* __restrict__ b3,
    float* __restrict__ out) {
  __shared__ __align__(16) char buf[65536];   // h0 -> h1 (in place), then out-staging

  const int tid = threadIdx.x;
  const int bid = blockIdx.x;
  const int a0i = (bid >> 5) * 8;    // 64 a-tile groups of 8
  const int bb0 = (bid & 31) * 16;   // 32 b-tile groups

  const int lane = tid & 63, wv = tid >> 6;
  const int c = lane & 31, l5 = lane >> 5;
  const f32x4 vzero = {0.f, 0.f, 0.f, 0.f};

  const unsigned short* fb1 = W1f + wv * 512 + lane * 8;   // + kt*4096 (ushort units)
  const unsigned short* fb2 = W2f + wv * 512 + lane * 8;

  // issue layer-1 A prefetch immediately; latency hides under the h0 build
  bf16x8 a0 = *(const bf16x8*)(fb1);
  bf16x8 a1 = *(const bf16x8*)(fb1 + 4096);

  // ---- build h0: thread (wv, lane) fills 16B of frag(kt, mt = wv&3) for 8 kt values ----
  // h0[m][k] = relu(hx'[a0i + m>>4][k] + hy[bb0 + (m&15)][k]),  m = (wv&3)*32 + c
  {
    int mt_b = wv & 3;
    int kbase = (wv >> 2) * 8;           // kt range [kbase, kbase+8)
    int m = mt_b * 32 + c;
    const float* pxr = hx + (a0i + (m >> 4)) * NHID + l5 * 8;
    const float* pyr = hy + (bb0 + (m & 15)) * NHID + l5 * 8;
    char* wbase = buf + (kbase * 4 + mt_b) * 1024 + lane * 16;
#pragma unroll
    for (int j = 0; j < 8; ++j) {
      int ko = (kbase + j) * 16;
      f32x4 x0 = *(const f32x4*)(pxr + ko);
      f32x4 x1 = *(const f32x4*)(pxr + ko + 4);
      f32x4 y0 = *(const f32x4*)(pyr + ko);
      f32x4 y1 = *(const f32x4*)(pyr + ko + 4);
      f32x4 a = __builtin_elementwise_max(x0 + y0, vzero);
      f32x4 b = __builtin_elementwise_max(x1 + y1, vzero);
      uint4 pk;
      pk.x = pk2bf(a[0], a[1]);
      pk.y = pk2bf(a[2], a[3]);
      pk.z = pk2bf(b[0], b[1]);
      pk.w = pk2bf(b[2], b[3]);
      *(uint4*)(wbase + j * 4096) = pk;
    }
  }
  __syncthreads();

  const char* src_lane = buf + lane * 16;
  f32x16 acc[4];
  bf16x8 w2a0, w2a1;

  // ---- layer 1 (also prefetches layer-2 A frags in its tail) ----
  layer_loop<true>(fb1, src_lane, acc, a0, a1, fb2, w2a0, w2a1);
  __syncthreads();

  // ---- layer-1 epilogue: h1[m][g] = relu(acc + b1) back into fragment-major LDS ----
  // acc[mt][r]: m = mt*32 + c, g = wv*32 + rg*8 + l5*4 + (r&3)  (rg = r>>2).
  // Dest frag f' = (g>>4)*4 + (m>>5) = (wv*2 + (rg>>1))*4 + mt,
  //   lane slot l' = c + 32*(rg&1), byte l'*16 + l5*8 (8B store of 4 bf16).
  {
#pragma unroll
    for (int rg = 0; rg < 4; ++rg) {
      f32x4 bv = *(const f32x4*)(bias1 + wv * 32 + rg * 8 + l5 * 4);
      char* wa = buf + (c + ((rg & 1) << 5)) * 16 + l5 * 8;
      int fbase = (wv * 2 + (rg >> 1)) * 4;
#pragma unroll
      for (int mt = 0; mt < 4; ++mt) {
        f32x16 v = acc[mt];
        f32x4 t = {v[rg * 4 + 0], v[rg * 4 + 1], v[rg * 4 + 2], v[rg * 4 + 3]};
        t = __builtin_elementwise_max(t + bv, vzero);
        uint2 pk;
        pk.x = pk2bf(t[0], t[1]);
        pk.y = pk2bf(t[2], t[3]);
        *(uint2*)(wa + (fbase + mt) * 1024) = pk;
      }
    }
  }
  __syncthreads();

  // ---- layer 2 + head folded into registers ----
  {
    bf16x8 d0, d1;   // dummies (no further prefetch)
    layer_loop<false>(fb2, src_lane, acc, w2a0, w2a1, fb2, d0, d1);
  }

  float s[4];
  {
    f32x4 sv[4];
#pragma unroll
    for (int mt = 0; mt < 4; ++mt) sv[mt] = vzero;
#pragma unroll
    for (int rg = 0; rg < 4; ++rg) {
      int g0 = wv * 32 + rg * 8 + l5 * 4;
      f32x4 bv  = *(const f32x4*)(bias2 + g0);
      f32x4 wvv = *(const f32x4*)(w3 + g0);
#pragma unroll
      for (int mt = 0; mt < 4; ++mt) {
        f32x16 v = acc[mt];
        f32x4 t = {v[rg * 4 + 0], v[rg * 4 + 1], v[rg * 4 + 2], v[rg * 4 + 3]};
        t = __builtin_elementwise_max(t + bv, vzero);
        sv[mt] += t * wvv;
      }
    }
#pragma unroll
    for (int mt = 0; mt < 4; ++mt) {
      float t = sv[mt][0] + sv[mt][1] + sv[mt][2] + sv[mt][3];
      t += __shfl_xor(t, 32);            // combine the two l5 halves (different g-quads)
      s[mt] = t;
    }
  }

  __syncthreads();                    // all LDS reads of layer-2 done; reuse buf as staging
  float* stg = (float*)buf;           // [8 waves][128 m]
  if (l5 == 0) {
#pragma unroll
    for (int mt = 0; mt < 4; ++mt) stg[wv * 128 + mt * 32 + c] = s[mt];
  }
  __syncthreads();

  if (tid < 128) {
    float v = b3[0];
#pragma unroll
    for (int w = 0; w < 8; ++w) v += stg[w * 128 + tid];
    out[(a0i + (tid >> 4)) * NB + bb0 + (tid & 15)] = v;
  }
}

extern "C" void kernel_launch(void* const* d_in, const int* in_sizes, int n_in,
                              void* d_out, int out_size, void* d_ws, size_t ws_size,
                              hipStream_t stream) {
  const float* x  = (const float*)d_in[0];
  const float* y  = (const float*)d_in[1];
  const float* W0 = (const float*)d_in[2];
  const float* b0 = (const float*)d_in[3];
  const float* W1 = (const float*)d_in[4];
  const float* b1 = (const float*)d_in[5];
  const float* W2 = (const float*)d_in[6];
  const float* b2 = (const float*)d_in[7];
  const float* W3 = (const float*)d_in[8];
  const float* b3 = (const float*)d_in[9];
  float* out = (float*)d_out;

  char* ws = (char*)d_ws;
  float* hx = (float*)ws;                               // 512*256*4 = 512 KB
  float* hy = (float*)(ws + 524288);                    // 512 KB
  unsigned short* W1f = (unsigned short*)(ws + 1048576);          // 128 KB
  unsigned short* W2f = (unsigned short*)(ws + 1048576 + 131072); // 128 KB

  k_setup<<<dim3(256), dim3(256), 0, stream>>>(x, y, W0, b0, W1, W2, hx, hy, W1f, W2f);
  k_main<<<dim3(2048), dim3(512), 0, stream>>>(hx, hy, W1f, W2f, b1, b2, W3, b3, out);
}